// Round 1
// baseline (736.088 us; speedup 1.0000x reference)
//
#include <hip/hip_runtime.h>

// SoftTriple loss, MI355X. B=256, E=512, C=8192, K=10 (padded to 16).
// ws layout (bytes):
//   [0, 134217728)            w_pad  bf16 [8192*16][512]  (pad rows zeroed)
//   [134217728, 134479872)    emb_bf16 [256][512]
//   [134479872, 142868480)    h float [256][8192]
//   [142868480, +8)           accum[2] = {loss_sum, reg_sum}
// total ~136.3 MiB

typedef __bf16 bf16;
typedef bf16 bf16x8 __attribute__((ext_vector_type(8)));
typedef float f32x4 __attribute__((ext_vector_type(4)));

#define NCLASS 8192
#define KC 10
#define KPAD 16
#define EDIM 512
#define BATCH 256

__device__ inline void load_lds16(const void* g, void* l) {
    __builtin_amdgcn_global_load_lds(
        (const __attribute__((address_space(1))) void*)g,
        (__attribute__((address_space(3))) void*)l, 16, 0, 0);
}

// ---------------- kernel 1: normalize + gram + padded bf16 write ----------
__global__ __launch_bounds__(256) void prep_kernel(
    const float* __restrict__ fc, bf16* __restrict__ wpad,
    float* __restrict__ reg_accum)
{
    __shared__ float rows[KC * EDIM];   // 20 KB
    __shared__ float s_invn[KC];
    const int c = blockIdx.x;
    const int t = threadIdx.x;
    const int wave = t >> 6, lane = t & 63;

    const float* src = fc + (size_t)c * (KC * EDIM);
    for (int i = t; i < KC * EDIM; i += 256) rows[i] = src[i];
    __syncthreads();

    // row norms: wave w handles rows w, w+4, w+8
    for (int r = wave; r < KC; r += 4) {
        float s = 0.f;
        #pragma unroll
        for (int j = 0; j < 8; ++j) {
            float v = rows[r * EDIM + lane + j * 64];
            s += v * v;
        }
        #pragma unroll
        for (int off = 32; off; off >>= 1) s += __shfl_xor(s, off);
        if (lane == 0) s_invn[r] = 1.0f / fmaxf(sqrtf(s), 1e-12f);
    }
    __syncthreads();

    // write normalized bf16, padded to 16 rows
    bf16* dst = wpad + (size_t)c * (KPAD * EDIM);
    for (int i = t; i < KC * EDIM; i += 256) {
        int r = i >> 9;
        dst[i] = (bf16)(rows[i] * s_invn[r]);
    }
    for (int i = t; i < (KPAD - KC) * EDIM; i += 256)
        dst[KC * EDIM + i] = (bf16)0.0f;

    // gram regularizer: 45 strict-upper pairs, fp32 accuracy
    float part = 0.f;
    for (int p = wave; p < 45; p += 4) {
        int i = 0, pp = p;
        while (pp >= 9 - i) { pp -= 9 - i; ++i; }
        int j = i + 1 + pp;
        float s = 0.f;
        #pragma unroll
        for (int u = 0; u < 8; ++u)
            s += rows[i * EDIM + lane + u * 64] * rows[j * EDIM + lane + u * 64];
        #pragma unroll
        for (int off = 32; off; off >>= 1) s += __shfl_xor(s, off);
        if (lane == 0) {
            float sub = 1.0f - s * s_invn[i] * s_invn[j];
            if (sub <= 0.0f) sub = 1e-10f;
            part += sqrtf(2.0f * sub);
        }
    }
    if (lane == 0) atomicAdd(reg_accum, part);
}

// ---------------- kernel 1b: embeddings fp32 -> bf16 ----------------------
__global__ __launch_bounds__(256) void conv_kernel(
    const float* __restrict__ e, bf16* __restrict__ out)
{
    int i = blockIdx.x * 256 + threadIdx.x;   // grid 512 covers 131072 exactly
    out[i] = (bf16)e[i];
}

// ---------------- kernel 2: GEMM (256 x 131072 x 512) + softmax-K epilogue
// tile: BM=256 (full M), BN=128 (= 8 classes), BK=32; 512 threads = 8 waves,
// wave grid 4(m) x 2(n), each wave 64x64 = 4x4 MFMA 16x16x32 tiles.
__global__ __launch_bounds__(512) void gemm_h_kernel(
    const bf16* __restrict__ A,    // [256][512] emb bf16
    const bf16* __restrict__ W,    // [131072][512] padded normalized centers
    float* __restrict__ h)         // [256][8192]
{
    __shared__ bf16 As[256 * 32];  // 16 KB
    __shared__ bf16 Bs[128 * 32];  //  8 KB
    const int tid = threadIdx.x;
    const int wave = tid >> 6, lane = tid & 63;
    const int wm = wave >> 1, wn = wave & 1;
    const int n0 = blockIdx.x * 128;

    f32x4 acc[4][4];
    #pragma unroll
    for (int mt = 0; mt < 4; ++mt)
        #pragma unroll
        for (int nt = 0; nt < 4; ++nt)
            acc[mt][nt] = (f32x4){0.f, 0.f, 0.f, 0.f};

    const int lrow = lane >> 2;         // 0..15: row within a wave's 16-row slab
    const int lcol = (lane & 3) * 8;    // elem offset of 16B chunk

    for (int kb = 0; kb < EDIM; kb += 32) {
        // stage A: 2 passes x 8 waves x 16 rows = 256 rows of 32 elems
        #pragma unroll
        for (int p = 0; p < 2; ++p) {
            int row = p * 128 + wave * 16 + lrow;
            load_lds16(A + row * EDIM + kb + lcol,
                       As + (p * 128 + wave * 16) * 32);
        }
        // stage B: 8 waves x 16 rows = 128 rows
        {
            int row = wave * 16 + lrow;
            load_lds16(W + (size_t)(n0 + row) * EDIM + kb + lcol,
                       Bs + (wave * 16) * 32);
        }
        __syncthreads();

        const int q8 = (lane >> 4) * 8;
        bf16x8 af[4], bfr[4];
        #pragma unroll
        for (int mt = 0; mt < 4; ++mt)
            af[mt] = *(const bf16x8*)&As[(wm * 64 + mt * 16 + (lane & 15)) * 32 + q8];
        #pragma unroll
        for (int nt = 0; nt < 4; ++nt)
            bfr[nt] = *(const bf16x8*)&Bs[(wn * 64 + nt * 16 + (lane & 15)) * 32 + q8];
        #pragma unroll
        for (int mt = 0; mt < 4; ++mt)
            #pragma unroll
            for (int nt = 0; nt < 4; ++nt)
                acc[mt][nt] = __builtin_amdgcn_mfma_f32_16x16x32_bf16(
                    af[mt], bfr[nt], acc[mt][nt], 0, 0, 0);
        __syncthreads();
    }

    // epilogue: per (m-row, class) softmax over k (cols 0..9 valid of 16)
    const int col = lane & 15;
    const int quad = lane >> 4;
    const bool valid = col < KC;
    #pragma unroll
    for (int mt = 0; mt < 4; ++mt) {
        #pragma unroll
        for (int nt = 0; nt < 4; ++nt) {
            int cls = blockIdx.x * 8 + wn * 4 + nt;
            #pragma unroll
            for (int r = 0; r < 4; ++r) {
                float x = acc[mt][nt][r];
                float xm = valid ? x : -1e30f;
                #pragma unroll
                for (int off = 1; off < 16; off <<= 1)
                    xm = fmaxf(xm, __shfl_xor(xm, off));
                float e = valid ? __expf(10.0f * (x - xm)) : 0.0f;
                float s1 = e, s2 = e * x;
                #pragma unroll
                for (int off = 1; off < 16; off <<= 1) {
                    s1 += __shfl_xor(s1, off);
                    s2 += __shfl_xor(s2, off);
                }
                if (col == 0) {
                    int b = wm * 64 + mt * 16 + quad * 4 + r;
                    h[(size_t)b * NCLASS + cls] = s2 / s1;
                }
            }
        }
    }
}

// ---------------- kernel 3: cross-entropy over 8192 classes per row -------
__global__ __launch_bounds__(256) void ce_kernel(
    const float* __restrict__ h, const int* __restrict__ labels,
    float* __restrict__ accum)
{
    __shared__ float redm[4];
    __shared__ float reds[4];
    const int b = blockIdx.x, t = threadIdx.x;
    const int wave = t >> 6, lane = t & 63;
    const int lbl = labels[b];
    const float* hb = h + (size_t)b * NCLASS;

    float lg_cache[32];
    float mx = -1e30f;
    #pragma unroll
    for (int k = 0; k < 32; ++k) {
        int c = t + k * 256;
        float lg = 10.0f * hb[c];
        if (c == lbl) lg -= 0.1f;          // LMD * MARGIN
        lg_cache[k] = lg;
        mx = fmaxf(mx, lg);
    }
    #pragma unroll
    for (int off = 32; off; off >>= 1) mx = fmaxf(mx, __shfl_xor(mx, off));
    if (lane == 0) redm[wave] = mx;
    __syncthreads();
    mx = fmaxf(fmaxf(redm[0], redm[1]), fmaxf(redm[2], redm[3]));

    float s = 0.f;
    #pragma unroll
    for (int k = 0; k < 32; ++k) s += __expf(lg_cache[k] - mx);
    #pragma unroll
    for (int off = 32; off; off >>= 1) s += __shfl_xor(s, off);
    if (lane == 0) reds[wave] = s;
    __syncthreads();
    if (t == 0) {
        s = reds[0] + reds[1] + reds[2] + reds[3];
        float logit_l = 10.0f * (hb[lbl] - 0.01f);
        float loss_b = mx + logf(s) - logit_l;   // -logp[label]
        atomicAdd(accum, loss_b);
    }
}

// ---------------- kernel 4: combine --------------------------------------
__global__ void final_kernel(const float* __restrict__ accum,
                             float* __restrict__ out)
{
    out[0] = accum[0] * (1.0f / 256.0f)
           + 0.2f * (accum[1] * (1.0f / 737280.0f));  // C*K*(K-1) = 737280
}

extern "C" void kernel_launch(void* const* d_in, const int* in_sizes, int n_in,
                              void* d_out, int out_size, void* d_ws, size_t ws_size,
                              hipStream_t stream) {
    const float* emb    = (const float*)d_in[0];   // [256][512]
    const int*   labels = (const int*)d_in[1];     // [256]
    const float* fc     = (const float*)d_in[2];   // [81920][512]
    float* out = (float*)d_out;

    char* ws = (char*)d_ws;
    bf16*  wpad  = (bf16*)ws;                              // 134217728 B
    bf16*  embb  = (bf16*)(ws + 134217728);                //    262144 B
    float* h     = (float*)(ws + 134479872);               //   8388608 B
    float* accum = (float*)(ws + 142868480);               // 2 floats

    hipMemsetAsync(accum, 0, 2 * sizeof(float), stream);
    prep_kernel<<<NCLASS, 256, 0, stream>>>(fc, wpad, accum + 1);
    conv_kernel<<<512, 256, 0, stream>>>(emb, embb);
    gemm_h_kernel<<<131072 / 128, 512, 0, stream>>>(embb, wpad, h);
    ce_kernel<<<BATCH, 256, 0, stream>>>(h, labels, accum);
    final_kernel<<<1, 1, 0, stream>>>(accum, out);
}

// Round 2
// 326.619 us; speedup vs baseline: 2.2537x; 2.2537x over previous
//
#include <hip/hip_runtime.h>

// SoftTriple loss, MI355X. B=256, E=512, C=8192, K=10 (padded to 16).
// ws layout (bytes):
//   [0, 134217728)            w_pad  bf16 [8192*16][512]  (pad rows zeroed)
//   [134217728, 134479872)    emb_bf16 [256][512]
//   [134479872, 142868480)    h float [256][8192]
//   [142868480, 142901248)    gram_part float[8192]
//   [142901248, 142902272)    ce_part  float[256]

typedef __bf16 bf16;
typedef bf16 bf16x8 __attribute__((ext_vector_type(8)));
typedef float f32x4 __attribute__((ext_vector_type(4)));

#define NCLASS 8192
#define KC 10
#define KPAD 16
#define EDIM 512
#define BATCH 256

__device__ inline void load_lds16(const void* g, void* l) {
    __builtin_amdgcn_global_load_lds(
        (const __attribute__((address_space(1))) void*)g,
        (__attribute__((address_space(3))) void*)l, 16, 0, 0);
}

// ---------------- kernel 1: normalize + gram + padded bf16 write ----------
// No atomics: per-class gram partial goes to gram_part[c].
__global__ __launch_bounds__(256) void prep_kernel(
    const float* __restrict__ fc, bf16* __restrict__ wpad,
    float* __restrict__ gram_part)
{
    __shared__ float rows[KC * EDIM];   // 20 KB
    __shared__ float s_invn[KC];
    __shared__ float s_wsum[4];
    const int c = blockIdx.x;
    const int t = threadIdx.x;
    const int wave = t >> 6, lane = t & 63;

    // vectorized load: 1280 float4 = 5120 floats
    const float4* src = (const float4*)(fc + (size_t)c * (KC * EDIM));
    float4* rows4 = (float4*)rows;
    #pragma unroll
    for (int i = 0; i < 5; ++i) rows4[t + i * 256] = src[t + i * 256];
    __syncthreads();

    // row norms: wave w handles rows w, w+4, w+8
    for (int r = wave; r < KC; r += 4) {
        float s = 0.f;
        #pragma unroll
        for (int j = 0; j < 8; ++j) {
            float v = rows[r * EDIM + lane + j * 64];
            s += v * v;
        }
        #pragma unroll
        for (int off = 32; off; off >>= 1) s += __shfl_xor(s, off);
        if (lane == 0) s_invn[r] = 1.0f / fmaxf(sqrtf(s), 1e-12f);
    }
    __syncthreads();

    // write normalized bf16, padded to 16 rows, 16B stores.
    // 1024 chunks of 8 bf16; chunk j -> row j>>6 (64 chunks/row)
    bf16x8* dst = (bf16x8*)(wpad + (size_t)c * (KPAD * EDIM));
    #pragma unroll
    for (int p = 0; p < 4; ++p) {
        int j = t + p * 256;
        int r = j >> 6;
        bf16x8 v;
        if (r < KC) {
            float inv = s_invn[r];
            float4 a = *(const float4*)(rows + j * 8);
            float4 b = *(const float4*)(rows + j * 8 + 4);
            v[0] = (bf16)(a.x * inv); v[1] = (bf16)(a.y * inv);
            v[2] = (bf16)(a.z * inv); v[3] = (bf16)(a.w * inv);
            v[4] = (bf16)(b.x * inv); v[5] = (bf16)(b.y * inv);
            v[6] = (bf16)(b.z * inv); v[7] = (bf16)(b.w * inv);
        } else {
            #pragma unroll
            for (int u = 0; u < 8; ++u) v[u] = (bf16)0.0f;
        }
        dst[j] = v;
    }

    // gram regularizer: 45 strict-upper pairs, fp32 accuracy
    float part = 0.f;
    for (int p = wave; p < 45; p += 4) {
        int i = 0, pp = p;
        while (pp >= 9 - i) { pp -= 9 - i; ++i; }
        int j = i + 1 + pp;
        float s = 0.f;
        #pragma unroll
        for (int u = 0; u < 8; ++u)
            s += rows[i * EDIM + lane + u * 64] * rows[j * EDIM + lane + u * 64];
        #pragma unroll
        for (int off = 32; off; off >>= 1) s += __shfl_xor(s, off);
        if (lane == 0) {
            float sub = 1.0f - s * s_invn[i] * s_invn[j];
            if (sub <= 0.0f) sub = 1e-10f;
            part += sqrtf(2.0f * sub);
        }
    }
    if (lane == 0) s_wsum[wave] = part;
    __syncthreads();
    if (t == 0) gram_part[c] = s_wsum[0] + s_wsum[1] + s_wsum[2] + s_wsum[3];
}

// ---------------- kernel 1b: embeddings fp32 -> bf16 ----------------------
__global__ __launch_bounds__(256) void conv_kernel(
    const float* __restrict__ e, bf16* __restrict__ out)
{
    int i = blockIdx.x * 256 + threadIdx.x;   // 64 blocks * 256 * 8 = 131072
    float4 a = ((const float4*)e)[i * 2];
    float4 b = ((const float4*)e)[i * 2 + 1];
    bf16x8 v;
    v[0] = (bf16)a.x; v[1] = (bf16)a.y; v[2] = (bf16)a.z; v[3] = (bf16)a.w;
    v[4] = (bf16)b.x; v[5] = (bf16)b.y; v[6] = (bf16)b.z; v[7] = (bf16)b.w;
    ((bf16x8*)out)[i] = v;
}

// ---------------- kernel 2: GEMM (131072 x 256 x 512) + softmax-K epilogue
// SWAPPED operands: W rows are the M-operand so the per-class k index lands
// in (quad, reg) of the C/D layout -> k-softmax is 3 reg-ops + 2 shuffles.
// tile: BM=128 (8 classes), BN=256 (full batch), BK=32; 512 threads = 8
// waves, wave grid 2(m) x 4(n), each wave 64x64 = 4x4 MFMA 16x16x32 tiles.
__global__ __launch_bounds__(512) void gemm_h_kernel(
    const bf16* __restrict__ W,    // [131072][512] padded normalized centers
    const bf16* __restrict__ A,    // [256][512] emb bf16
    float* __restrict__ h)         // [256][8192]
{
    __shared__ bf16 Ws[128 * 32];  //  8 KB
    __shared__ bf16 Es[256 * 32];  // 16 KB
    const int tid = threadIdx.x;
    const int wave = tid >> 6, lane = tid & 63;
    const int wm = wave & 1, wn = wave >> 1;
    const size_t m0 = (size_t)blockIdx.x * 128;

    f32x4 acc[4][4];
    #pragma unroll
    for (int mt = 0; mt < 4; ++mt)
        #pragma unroll
        for (int nt = 0; nt < 4; ++nt)
            acc[mt][nt] = (f32x4){0.f, 0.f, 0.f, 0.f};

    const int lrow = lane >> 2;         // 0..15: row within a wave's 16-row slab
    const int lcol = (lane & 3) * 8;    // elem offset of 16B chunk

    for (int kb = 0; kb < EDIM; kb += 32) {
        // stage W: 8 waves x 16 rows = 128 rows of 32 elems
        load_lds16(W + (m0 + wave * 16 + lrow) * EDIM + kb + lcol,
                   Ws + (wave * 16) * 32);
        // stage E: 2 passes x 128 rows = 256 rows
        #pragma unroll
        for (int p = 0; p < 2; ++p) {
            int row = p * 128 + wave * 16 + lrow;
            load_lds16(A + row * EDIM + kb + lcol,
                       Es + (p * 128 + wave * 16) * 32);
        }
        __syncthreads();

        const int q8 = (lane >> 4) * 8;
        bf16x8 wf[4], ef[4];
        #pragma unroll
        for (int mt = 0; mt < 4; ++mt)
            wf[mt] = *(const bf16x8*)&Ws[(wm * 64 + mt * 16 + (lane & 15)) * 32 + q8];
        #pragma unroll
        for (int nt = 0; nt < 4; ++nt)
            ef[nt] = *(const bf16x8*)&Es[(wn * 64 + nt * 16 + (lane & 15)) * 32 + q8];
        #pragma unroll
        for (int mt = 0; mt < 4; ++mt)
            #pragma unroll
            for (int nt = 0; nt < 4; ++nt)
                acc[mt][nt] = __builtin_amdgcn_mfma_f32_16x16x32_bf16(
                    wf[mt], ef[nt], acc[mt][nt], 0, 0, 0);
        __syncthreads();
    }

    // epilogue: D row = quad*4+reg = k within class, D col = lane&15 = batch
    const int col = lane & 15;
    const int quad = lane >> 4;
    #pragma unroll
    for (int mt = 0; mt < 4; ++mt) {
        int cls = blockIdx.x * 8 + wm * 4 + mt;
        #pragma unroll
        for (int nt = 0; nt < 4; ++nt) {
            int b = wn * 64 + nt * 16 + col;
            float xm = -1e30f;
            #pragma unroll
            for (int r = 0; r < 4; ++r)
                if (quad * 4 + r < KC) xm = fmaxf(xm, acc[mt][nt][r]);
            xm = fmaxf(xm, __shfl_xor(xm, 16));
            xm = fmaxf(xm, __shfl_xor(xm, 32));
            float s1 = 0.f, s2 = 0.f;
            #pragma unroll
            for (int r = 0; r < 4; ++r) {
                if (quad * 4 + r < KC) {
                    float x = acc[mt][nt][r];
                    float e = __expf(10.0f * (x - xm));
                    s1 += e; s2 += e * x;
                }
            }
            s1 += __shfl_xor(s1, 16); s1 += __shfl_xor(s1, 32);
            s2 += __shfl_xor(s2, 16); s2 += __shfl_xor(s2, 32);
            if (quad == 0) h[(size_t)b * NCLASS + cls] = s2 / s1;
        }
    }
}

// ---------------- kernel 3: cross-entropy over 8192 classes per row -------
__global__ __launch_bounds__(256) void ce_kernel(
    const float* __restrict__ h, const int* __restrict__ labels,
    float* __restrict__ ce_part)
{
    __shared__ float redm[4];
    __shared__ float reds[4];
    const int b = blockIdx.x, t = threadIdx.x;
    const int wave = t >> 6, lane = t & 63;
    const int lbl = labels[b];
    const float* hb = h + (size_t)b * NCLASS;

    float lg_cache[32];
    float mx = -1e30f;
    #pragma unroll
    for (int k = 0; k < 32; ++k) {
        int c = t + k * 256;
        float lg = 10.0f * hb[c];
        if (c == lbl) lg -= 0.1f;          // LMD * MARGIN
        lg_cache[k] = lg;
        mx = fmaxf(mx, lg);
    }
    #pragma unroll
    for (int off = 32; off; off >>= 1) mx = fmaxf(mx, __shfl_xor(mx, off));
    if (lane == 0) redm[wave] = mx;
    __syncthreads();
    mx = fmaxf(fmaxf(redm[0], redm[1]), fmaxf(redm[2], redm[3]));

    float s = 0.f;
    #pragma unroll
    for (int k = 0; k < 32; ++k) s += __expf(lg_cache[k] - mx);
    #pragma unroll
    for (int off = 32; off; off >>= 1) s += __shfl_xor(s, off);
    if (lane == 0) reds[wave] = s;
    __syncthreads();
    if (t == 0) {
        s = reds[0] + reds[1] + reds[2] + reds[3];
        float logit_l = 10.0f * (hb[lbl] - 0.01f);
        ce_part[b] = mx + logf(s) - logit_l;   // -logp[label]
    }
}

// ---------------- kernel 4: reduce partials + combine ---------------------
__global__ __launch_bounds__(256) void final_kernel(
    const float* __restrict__ gram_part, const float* __restrict__ ce_part,
    float* __restrict__ out)
{
    __shared__ float red[4];
    const int t = threadIdx.x, wave = t >> 6, lane = t & 63;
    float g = 0.f;
    #pragma unroll
    for (int i = 0; i < 32; ++i) g += gram_part[t + i * 256];
    float val = ce_part[t] * (1.0f / 256.0f)
              + g * (0.2f / 737280.0f);       // C*K*(K-1) = 737280
    #pragma unroll
    for (int off = 32; off; off >>= 1) val += __shfl_xor(val, off);
    if (lane == 0) red[wave] = val;
    __syncthreads();
    if (t == 0) out[0] = red[0] + red[1] + red[2] + red[3];
}

extern "C" void kernel_launch(void* const* d_in, const int* in_sizes, int n_in,
                              void* d_out, int out_size, void* d_ws, size_t ws_size,
                              hipStream_t stream) {
    const float* emb    = (const float*)d_in[0];   // [256][512]
    const int*   labels = (const int*)d_in[1];     // [256]
    const float* fc     = (const float*)d_in[2];   // [81920][512]
    float* out = (float*)d_out;

    char* ws = (char*)d_ws;
    bf16*  wpad      = (bf16*)ws;                        // 134217728 B
    bf16*  embb      = (bf16*)(ws + 134217728);          //    262144 B
    float* h         = (float*)(ws + 134479872);         //   8388608 B
    float* gram_part = (float*)(ws + 142868480);         //     32768 B
    float* ce_part   = (float*)(ws + 142901248);         //      1024 B

    prep_kernel<<<NCLASS, 256, 0, stream>>>(fc, wpad, gram_part);
    conv_kernel<<<64, 256, 0, stream>>>(emb, embb);
    gemm_h_kernel<<<131072 / 128, 512, 0, stream>>>(wpad, embb, h);
    ce_kernel<<<BATCH, 256, 0, stream>>>(h, labels, ce_part);
    final_kernel<<<1, 256, 0, stream>>>(gram_part, ce_part, out);
}